// Round 3
// baseline (243.400 us; speedup 1.0000x reference)
//
#include <hip/hip_runtime.h>
#include <math.h>

#define NN     512     // N (columns of x)
#define KK     513     // K
#define BB     65536   // batch
#define TROWS  512     // table rows, t = 0..511
#define TCOLS  513     // table cols, g = 0..512

typedef int iv4 __attribute__((ext_vector_type(4)));  // native vector: ok for nontemporal builtin

// T[t][g][c]:
//   t == 0                      -> 0 (step t=0 has no W term)
//   1 <= g <= t                 -> log softmax(W[t-1][g-1])[c]
//   g == 0 or g == t+1 (edges)  -> log(1) = 0  (only reachable c gives log1)
//   anything else               -> unreachable, set 0
__global__ void build_table_kernel(const float* __restrict__ W, float* __restrict__ T) {
    int idx = blockIdx.x * blockDim.x + threadIdx.x;
    if (idx >= TROWS * TCOLS) return;
    int t = idx / TCOLS;
    int g = idx - t * TCOLS;
    float v0 = 0.f, v1 = 0.f;
    if (t >= 1 && g >= 1 && g <= t) {
        const float* w = W + ((size_t)(t - 1) * (KK - 1) + (g - 1)) * 2;
        float w0 = w[0], w1 = w[1];
        float m  = fmaxf(w0, w1);
        float lse = m + logf(expf(w0 - m) + expf(w1 - m));
        v0 = w0 - lse;
        v1 = w1 - lse;
    }
    T[2 * idx + 0] = v0;
    T[2 * idx + 1] = v1;
}

// logE[k] = endW[k] - logsumexp(endW)   (513 entries), one wave
__global__ void build_endw_kernel(const float* __restrict__ endW, float* __restrict__ logE) {
    int lane = threadIdx.x;  // 0..63
    float vals[9];
    float m = -1e30f;
    #pragma unroll
    for (int k = 0; k < 9; ++k) {
        int i = lane + 64 * k;
        vals[k] = (i < KK) ? endW[i] : -1e30f;
        m = fmaxf(m, vals[k]);
    }
    #pragma unroll
    for (int d = 32; d >= 1; d >>= 1) m = fmaxf(m, __shfl_xor(m, d, 64));
    float s = 0.f;
    #pragma unroll
    for (int k = 0; k < 9; ++k) s += expf(vals[k] - m);  // -1e30 pads underflow to 0
    #pragma unroll
    for (int d = 32; d >= 1; d >>= 1) s += __shfl_xor(s, d, 64);
    float lse = m + logf(s);
    #pragma unroll
    for (int k = 0; k < 9; ++k) {
        int i = lane + 64 * k;
        if (i < KK) logE[i] = endW[i] - lse;
    }
}

// One thread per batch row; 64 lockstep lanes = 64 rows, so each gather
// instruction touches ONE table row t with binomially-concentrated g
// (hot set ~a few KB, L1/L2 resident).
//
// Structure: 16 fully-unrolled iterations of 32 columns (128 B of x each),
// 2-deep register prefetch of x. Gathers are issued before the next
// prefetch so the in-order vmcnt drain for gather consumption does not
// stall on the youngest x-load; each x-load gets ~1 full iteration
// (~500-700 cy of gathers+adds) to cover HBM latency.
// x loads are nontemporal: 128 MB streaming must not evict the 2.1 MB
// table from the per-XCD L2.
__global__ __launch_bounds__(256) void pc_main_kernel(
    const int* __restrict__ x, const float* __restrict__ T,
    const float* __restrict__ logE, float* __restrict__ out)
{
    const int row = blockIdx.x * blockDim.x + threadIdx.x;  // BB==grid*block exactly
    const iv4* xp = (const iv4*)(x + (size_t)row * NN);

    float a0 = 0.f, a1 = 0.f, a2 = 0.f, a3 = 0.f;
    int g = 0;

    iv4 c[8], n[8];
    #pragma unroll
    for (int j = 0; j < 8; ++j) c[j] = __builtin_nontemporal_load(&xp[j]);
    #pragma unroll
    for (int j = 0; j < 8; ++j) n[j] = __builtin_nontemporal_load(&xp[8 + j]);

    #pragma unroll
    for (int ch = 0; ch < 16; ++ch) {
        int xs[32];
        #pragma unroll
        for (int j = 0; j < 8; ++j) {
            xs[4 * j + 0] = c[j].x;
            xs[4 * j + 1] = c[j].y;
            xs[4 * j + 2] = c[j].z;
            xs[4 * j + 3] = c[j].w;
        }
        // issue all 32 gathers (addresses: 1026*t + 2*g + x; t const per site)
        float v[32];
        #pragma unroll
        for (int k = 0; k < 32; ++k) {
            g += xs[k];
            v[k] = T[(ch * 32 + k) * (2 * TCOLS) + 2 * g + xs[k]];
        }
        // rotate and prefetch chunk ch+2 (issued after the gathers)
        #pragma unroll
        for (int j = 0; j < 8; ++j) c[j] = n[j];
        if (ch < 14) {
            const iv4* p = xp + (ch + 2) * 8;
            #pragma unroll
            for (int j = 0; j < 8; ++j) n[j] = __builtin_nontemporal_load(&p[j]);
        }
        // accumulate (4 independent chains)
        #pragma unroll
        for (int k = 0; k < 32; ++k) {
            if      ((k & 3) == 0) a0 += v[k];
            else if ((k & 3) == 1) a1 += v[k];
            else if ((k & 3) == 2) a2 += v[k];
            else                   a3 += v[k];
        }
    }
    out[row] = (a0 + a1) + (a2 + a3) + logE[g];
}

extern "C" void kernel_launch(void* const* d_in, const int* in_sizes, int n_in,
                              void* d_out, int out_size, void* d_ws, size_t ws_size,
                              hipStream_t stream)
{
    const int*   x    = (const int*)d_in[0];
    const float* W    = (const float*)d_in[1];
    const float* endW = (const float*)d_in[2];
    float*       out  = (float*)d_out;

    float* T    = (float*)d_ws;                                   // 512*513*2 f32 = 2,101,248 B
    float* logE = (float*)((char*)d_ws + (size_t)TROWS * TCOLS * 2 * sizeof(float));

    {
        int total  = TROWS * TCOLS;
        int blocks = (total + 255) / 256;
        build_table_kernel<<<blocks, 256, 0, stream>>>(W, T);
    }
    build_endw_kernel<<<1, 64, 0, stream>>>(endW, logE);
    pc_main_kernel<<<BB / 256, 256, 0, stream>>>(x, T, logE, out);
}

// Round 4
// 240.007 us; speedup vs baseline: 1.0141x; 1.0141x over previous
//
#include <hip/hip_runtime.h>
#include <math.h>

#define NN      512     // N (columns of x)
#define KK      513     // K
#define BB      65536   // batch
#define TROWS   512     // table rows, t = 0..511
#define TCOLS   513     // table cols, g = 0..512
#define TSTRIDE (2 * TCOLS)   // 1026 floats per table row

#define BLK     64            // threads per block == rows per block (1 wave)
#define CHUNK   32            // columns per chunk
#define NCH     (NN / CHUNK)  // 16 chunks
#define LROW    (CHUNK + 1)   // 33 ints per LDS row (+1 pad -> 2-way banks, free)

typedef int iv4 __attribute__((ext_vector_type(4)));

// T[t][g][c]:
//   t == 0                      -> 0 (step t=0 has no W term)
//   1 <= g <= t                 -> log softmax(W[t-1][g-1])[c]
//   g == 0 or g == t+1 (edges)  -> log(1) = 0
__global__ void build_table_kernel(const float* __restrict__ W, float* __restrict__ T) {
    int idx = blockIdx.x * blockDim.x + threadIdx.x;
    if (idx >= TROWS * TCOLS) return;
    int t = idx / TCOLS;
    int g = idx - t * TCOLS;
    float v0 = 0.f, v1 = 0.f;
    if (t >= 1 && g >= 1 && g <= t) {
        const float* w = W + ((size_t)(t - 1) * (KK - 1) + (g - 1)) * 2;
        float w0 = w[0], w1 = w[1];
        float m  = fmaxf(w0, w1);
        float lse = m + logf(expf(w0 - m) + expf(w1 - m));
        v0 = w0 - lse;
        v1 = w1 - lse;
    }
    T[2 * idx + 0] = v0;
    T[2 * idx + 1] = v1;
}

// logE[k] = endW[k] - logsumexp(endW)   (513 entries), one wave
__global__ void build_endw_kernel(const float* __restrict__ endW, float* __restrict__ logE) {
    int lane = threadIdx.x;  // 0..63
    float vals[9];
    float m = -1e30f;
    #pragma unroll
    for (int k = 0; k < 9; ++k) {
        int i = lane + 64 * k;
        vals[k] = (i < KK) ? endW[i] : -1e30f;
        m = fmaxf(m, vals[k]);
    }
    #pragma unroll
    for (int d = 32; d >= 1; d >>= 1) m = fmaxf(m, __shfl_xor(m, d, 64));
    float s = 0.f;
    #pragma unroll
    for (int k = 0; k < 9; ++k) s += expf(vals[k] - m);
    #pragma unroll
    for (int d = 32; d >= 1; d >>= 1) s += __shfl_xor(s, d, 64);
    float lse = m + logf(s);
    #pragma unroll
    for (int k = 0; k < 9; ++k) {
        int i = lane + 64 * k;
        if (i < KK) logE[i] = endW[i] - lse;
    }
}

// Block = 1 wave = 64 rows. Per 32-col chunk: coalesced nontemporal x load
// (lane -> 16B contiguous within a 128B row-run), LDS transpose (padded, 2-way
// banks = free), then per-thread row-local gathers: each gather instruction
// touches ONE table row t with binomially-clustered g (L1/L2-hot).
// Double-buffered LDS + 2 register staging sets: every x load has >=2
// iterations (~1600+ cy) before its ds_write needs it.
__global__ __launch_bounds__(BLK) void pc_main_kernel(
    const int* __restrict__ x, const float* __restrict__ T,
    const float* __restrict__ logE, float* __restrict__ out)
{
    __shared__ int lds[2][BLK * LROW];
    const int tid  = threadIdx.x;
    const int row0 = blockIdx.x * BLK;

    iv4 SA[8], SB[8];

    auto issue_load = [&](iv4 (&S)[8], int ch) {
        #pragma unroll
        for (int j = 0; j < 8; ++j) {
            int q  = tid + BLK * j;     // 0..511 over the chunk's 512 int4
            int r  = q >> 3;            // row within block (0..63)
            int c4 = q & 7;             // int4 index within the 32-col chunk
            const iv4* p = (const iv4*)(x + (size_t)(row0 + r) * NN + ch * CHUNK + c4 * 4);
            S[j] = __builtin_nontemporal_load(p);
        }
    };
    auto write_lds = [&](int buf, iv4 (&S)[8]) {
        #pragma unroll
        for (int j = 0; j < 8; ++j) {
            int q  = tid + BLK * j;
            int r  = q >> 3;
            int c4 = q & 7;
            int b  = r * LROW + c4 * 4;
            lds[buf][b + 0] = S[j].x;
            lds[buf][b + 1] = S[j].y;
            lds[buf][b + 2] = S[j].z;
            lds[buf][b + 3] = S[j].w;
        }
    };

    float a0 = 0.f, a1 = 0.f, a2 = 0.f, a3 = 0.f;
    int g = 0;

    // per-chunk compute: LDS row reads -> gathers; accumulation separated so
    // staging loads issued between them stay vmcnt-outstanding during gathers
    int   xs[CHUNK];
    float v[CHUNK];
    auto read_and_gather = [&](int buf, int ch) {
        #pragma unroll
        for (int k = 0; k < CHUNK; ++k) xs[k] = lds[buf][tid * LROW + k];
        const float* Tc = T + (size_t)ch * CHUNK * TSTRIDE;
        #pragma unroll
        for (int k = 0; k < CHUNK; ++k) {
            g += xs[k];
            v[k] = Tc[k * TSTRIDE + 2 * g + xs[k]];
        }
    };
    auto accumulate = [&]() {
        #pragma unroll
        for (int k = 0; k < CHUNK; ++k) {
            if      ((k & 3) == 0) a0 += v[k];
            else if ((k & 3) == 1) a1 += v[k];
            else if ((k & 3) == 2) a2 += v[k];
            else                   a3 += v[k];
        }
    };

    // prologue: SA=ch0 -> buf0; SB=ch1 in flight; SA reloads ch2
    issue_load(SA, 0);
    issue_load(SB, 1);
    write_lds(0, SA);        // waits vmcnt for SA only (SB stays outstanding)
    issue_load(SA, 2);
    __syncthreads();

    #pragma unroll
    for (int c2 = 0; c2 < NCH / 2; ++c2) {
        const int ce = 2 * c2;       // even chunk: compute buf0
        read_and_gather(0, ce);
        write_lds(1, SB);            // chunk ce+1 (loaded 2 iters ago)
        if (ce + 3 < NCH) issue_load(SB, ce + 3);
        accumulate();
        __syncthreads();

        const int co = ce + 1;       // odd chunk: compute buf1
        read_and_gather(1, co);
        if (co + 1 < NCH) write_lds(0, SA);   // chunk co+1
        if (co + 3 < NCH) issue_load(SA, co + 3);
        accumulate();
        __syncthreads();
    }

    out[row0 + tid] = (a0 + a1) + (a2 + a3) + logE[g];
}

extern "C" void kernel_launch(void* const* d_in, const int* in_sizes, int n_in,
                              void* d_out, int out_size, void* d_ws, size_t ws_size,
                              hipStream_t stream)
{
    const int*   x    = (const int*)d_in[0];
    const float* W    = (const float*)d_in[1];
    const float* endW = (const float*)d_in[2];
    float*       out  = (float*)d_out;

    float* T    = (float*)d_ws;                                   // 512*513*2 f32 = 2,101,248 B
    float* logE = (float*)((char*)d_ws + (size_t)TROWS * TCOLS * 2 * sizeof(float));

    {
        int total  = TROWS * TCOLS;
        int blocks = (total + 255) / 256;
        build_table_kernel<<<blocks, 256, 0, stream>>>(W, T);
    }
    build_endw_kernel<<<1, 64, 0, stream>>>(endW, logE);
    pc_main_kernel<<<BB / BLK, BLK, 0, stream>>>(x, T, logE, out);
}

// Round 6
// 202.019 us; speedup vs baseline: 1.2048x; 1.1880x over previous
//
#include <hip/hip_runtime.h>
#include <math.h>

#define NN      512     // N (columns of x)
#define KK      513     // K
#define BB      65536   // batch
#define TROWS   512     // table rows, t = 0..511
#define TCOLS   513     // table cols, g = 0..512
#define TSTRIDE (2 * TCOLS)   // 1026 floats per table row

#define RPB     64            // rows per block
#define NSEG    8             // segments per row
#define SEGW    64            // columns per segment
#define BLK     (RPB * NSEG)  // 512 threads = 8 waves
#define XSTR    129           // LDS row stride in u32 (128 + 1 pad: both phases bank-conflict-free)

typedef int iv4 __attribute__((ext_vector_type(4)));

// T[t][g][c]:
//   t == 0                      -> 0 (step t=0 has no W term)
//   1 <= g <= t                 -> log softmax(W[t-1][g-1])[c]
//   g == 0 or g == t+1 (edges)  -> log(1) = 0
__global__ void build_table_kernel(const float* __restrict__ W, float* __restrict__ T) {
    int idx = blockIdx.x * blockDim.x + threadIdx.x;
    if (idx >= TROWS * TCOLS) return;
    int t = idx / TCOLS;
    int g = idx - t * TCOLS;
    float v0 = 0.f, v1 = 0.f;
    if (t >= 1 && g >= 1 && g <= t) {
        const float* w = W + ((size_t)(t - 1) * (KK - 1) + (g - 1)) * 2;
        float w0 = w[0], w1 = w[1];
        float m  = fmaxf(w0, w1);
        float lse = m + logf(expf(w0 - m) + expf(w1 - m));
        v0 = w0 - lse;
        v1 = w1 - lse;
    }
    T[2 * idx + 0] = v0;
    T[2 * idx + 1] = v1;
}

// logE[k] = endW[k] - logsumexp(endW)   (513 entries), one wave
__global__ void build_endw_kernel(const float* __restrict__ endW, float* __restrict__ logE) {
    int lane = threadIdx.x;  // 0..63
    float vals[9];
    float m = -1e30f;
    #pragma unroll
    for (int k = 0; k < 9; ++k) {
        int i = lane + 64 * k;
        vals[k] = (i < KK) ? endW[i] : -1e30f;
        m = fmaxf(m, vals[k]);
    }
    #pragma unroll
    for (int d = 32; d >= 1; d >>= 1) m = fmaxf(m, __shfl_xor(m, d, 64));
    float s = 0.f;
    #pragma unroll
    for (int k = 0; k < 9; ++k) s += expf(vals[k] - m);
    #pragma unroll
    for (int d = 32; d >= 1; d >>= 1) s += __shfl_xor(s, d, 64);
    float lse = m + logf(s);
    #pragma unroll
    for (int k = 0; k < 9; ++k) {
        int i = lane + 64 * k;
        if (i < KK) logE[i] = endW[i] - lse;
    }
}

// Block = 512 threads = 64 rows x 8 segments (wave i = segment i).
// Phase 1: coalesced linear int4 load of the 64x512 x-tile (lane-consecutive
//          16B -> minimal TA line count), pack 4 ints -> 4 bytes (u32) in LDS.
// Phase 2: each thread popcounts its own 64-col segment (bytes are 0/1 ->
//          __popc of u32 counts them); tiny LDS exchange of segment sums
//          gives each thread its starting g (prefix over segments).
// Phase 3: 64 table gathers per thread; lanes of a wave share one table row
//          per instruction with binomially-clustered g (L1/L2-hot).
// Phase 4: per-row reduction of the 8 segment partials + endW term.
__global__ __launch_bounds__(BLK, 8) void pc_main_kernel(
    const int* __restrict__ x, const float* __restrict__ T,
    const float* __restrict__ logE, float* __restrict__ out)
{
    __shared__ unsigned int  xb[RPB * XSTR];        // packed 0/1 bytes, 4 cols per u32
    __shared__ int           segsum[NSEG * RPB];
    __shared__ float         partial[NSEG * RPB];

    const int tid  = threadIdx.x;
    const int row0 = blockIdx.x * RPB;

    // ---- phase 1: coalesced load + byte-pack into LDS ----
    {
        const iv4* tile = (const iv4*)(x + (size_t)row0 * NN);  // 8192 int4, linear
        #pragma unroll
        for (int j = 0; j < 16; ++j) {
            int i = tid + BLK * j;            // lane-consecutive -> perfect coalescing
            iv4 a = __builtin_nontemporal_load(&tile[i]);
            int r    = i >> 7;                // 128 int4 per row
            int col4 = i & 127;
            unsigned int m = (unsigned int)(a.x & 1)
                           | ((unsigned int)(a.y & 1) << 8)
                           | ((unsigned int)(a.z & 1) << 16)
                           | ((unsigned int)(a.w & 1) << 24);
            xb[r * XSTR + col4] = m;
        }
    }
    __syncthreads();

    // ---- phase 2: own-segment words + segment sums ----
    const int seg  = tid >> 6;    // wave index = segment
    const int lane = tid & 63;    // row within block

    unsigned int w[16];
    int ssum = 0;
    #pragma unroll
    for (int m = 0; m < 16; ++m) {
        w[m] = xb[lane * XSTR + seg * 16 + m];   // (lane + c) % 32 distinct -> conflict-free
        ssum += __popc(w[m]);                    // bytes are 0x00/0x01
    }
    segsum[seg * 64 + lane] = ssum;
    __syncthreads();

    int g = 0, gtot = 0;
    #pragma unroll
    for (int s = 0; s < NSEG; ++s) {
        int v = segsum[s * 64 + lane];
        if (s < seg) g += v;
        gtot += v;
    }

    // ---- phase 3: gathers ----
    float a0 = 0.f, a1 = 0.f, a2 = 0.f, a3 = 0.f;
    const float* Tbase = T + (size_t)seg * SEGW * TSTRIDE;
    #pragma unroll
    for (int m = 0; m < 16; ++m) {
        const float* Tm = Tbase + (size_t)(4 * m) * TSTRIDE;
        unsigned int wm = w[m];
        {
            int b0 = wm & 1;         g += b0; a0 += Tm[0 * TSTRIDE + 2 * g + b0];
            int b1 = (wm >> 8)  & 1; g += b1; a1 += Tm[1 * TSTRIDE + 2 * g + b1];
            int b2 = (wm >> 16) & 1; g += b2; a2 += Tm[2 * TSTRIDE + 2 * g + b2];
            int b3 = (wm >> 24) & 1; g += b3; a3 += Tm[3 * TSTRIDE + 2 * g + b3];
        }
    }
    partial[seg * 64 + lane] = (a0 + a1) + (a2 + a3);
    __syncthreads();

    // ---- phase 4: per-row reduction (wave 0 only) ----
    if (seg == 0) {
        float s = logE[gtot];
        #pragma unroll
        for (int t = 0; t < NSEG; ++t) s += partial[t * 64 + lane];
        out[row0 + lane] = s;
    }
}

extern "C" void kernel_launch(void* const* d_in, const int* in_sizes, int n_in,
                              void* d_out, int out_size, void* d_ws, size_t ws_size,
                              hipStream_t stream)
{
    const int*   x    = (const int*)d_in[0];
    const float* W    = (const float*)d_in[1];
    const float* endW = (const float*)d_in[2];
    float*       out  = (float*)d_out;

    float* T    = (float*)d_ws;                                   // 512*513*2 f32 = 2,101,248 B
    float* logE = (float*)((char*)d_ws + (size_t)TROWS * TCOLS * 2 * sizeof(float));

    {
        int total  = TROWS * TCOLS;
        int blocks = (total + 255) / 256;
        build_table_kernel<<<blocks, 256, 0, stream>>>(W, T);
    }
    build_endw_kernel<<<1, 64, 0, stream>>>(endW, logE);
    pc_main_kernel<<<BB / RPB, BLK, 0, stream>>>(x, T, logE, out);
}